// Round 1
// baseline (86.471 us; speedup 1.0000x reference)
//
#include <hip/hip_runtime.h>
#include <hip/hip_bf16.h>

// ---- types ----
typedef __attribute__((ext_vector_type(8))) short bfrag;   // 8 bf16 (4 VGPRs)
typedef __attribute__((ext_vector_type(4))) float f32x4;   // MFMA acc

typedef __attribute__((address_space(1))) const void GV;   // global src
typedef __attribute__((address_space(3))) void LV;         // lds dst

#define SLEN 2048
#define NBATCH 16
#define CIN 64
#define DM 512

// ---------------- norms (L1 over channels) + x -> bf16 cast ----------------
// one wave per row (row = b*S+s, 64 channels = 64 lanes), fully coalesced
__global__ void k_norms_xb(const float* __restrict__ x,
                           float* __restrict__ norms,
                           __hip_bfloat16* __restrict__ xb) {
    int tid = blockIdx.x * 256 + threadIdx.x;      // 2,097,152 threads
    float v = x[tid];
    xb[tid] = __float2bfloat16(v);
    float a = fabsf(v);
#pragma unroll
    for (int off = 32; off; off >>= 1) a += __shfl_xor(a, off);
    if ((threadIdx.x & 63) == 0) norms[tid >> 6] = a;
}

// ------------- conv_w (D,C,3) -> bf16 wt[d][kk], kk = k*64 + c -------------
__global__ void k_wt(const float* __restrict__ w, __hip_bfloat16* __restrict__ wt) {
    int i = blockIdx.x * 256 + threadIdx.x;        // 98304
    int d = i / 192, kk = i % 192;
    int c = kk & 63, k = kk >> 6;
    wt[i] = __float2bfloat16(w[d * 192 + c * 3 + k]);
}

// ------------- pe2[s][d] = PE(s,d) + tc_b[d]  (fp32 table, 4 MB) -----------
__global__ void k_pe(const float* __restrict__ tcb, float* __restrict__ pe2) {
    int i = blockIdx.x * 256 + threadIdx.x;        // 2048 * 256
    int s = i >> 8, h = i & 255;                   // h = d/2
    float dv = expf((float)(2 * h) * (-9.210340371976184f / 512.0f));
    float ang = (float)s * dv;
    float sv, cv;
    sincosf(ang, &sv, &cv);
    pe2[s * 512 + 2 * h]     = sv + tcb[2 * h];
    pe2[s * 512 + 2 * h + 1] = cv + tcb[2 * h + 1];
}

// ------------- tc[b][t]: wave-per-t backward scan with ballot --------------
__global__ void k_tc(const float* __restrict__ norms, float* __restrict__ tc) {
    int gid = blockIdx.x * 256 + threadIdx.x;
    int wave = gid >> 6;                           // 32768 waves = (b,t)
    int lane = threadIdx.x & 63;
    int b = wave >> 11, t = wave & 2047;
    const float* nb = norms + b * 2048;
    float thresh = 0.7f * (nb[t] + 1e-8f);         // (1-ETA)*(norm+EPS)
    int res = 0;
    for (int base = t - 1; base >= 0; base -= 64) {      // wave-uniform loop
        int s = base - lane;
        bool pred = (s >= 0) && (nb[s] < thresh);
        unsigned long long m = __ballot(pred);
        if (m) {                                   // smallest lane = largest s
            int l0 = __ffsll(m) - 1;
            res = t - (base - l0);
            break;
        }
    }
    if (lane == 0) tc[wave] = (float)res;
}

// ---------------- fused conv-GEMM + PE + tc-embed epilogue -----------------
// 128(M=s) x 128(N=d) tile, BK=64, 3 K-steps == the 3 conv taps.
// A-step-k rows are x rows shifted by (k-1) (circular) -> no im2col.
// T2 XOR-swizzle (16B granule, byte ^= (row&7)<<4) applied on BOTH the
// global source of global_load_lds and the ds_read side (rule 21).
__launch_bounds__(256)
__global__ void k_gemm(const __hip_bfloat16* __restrict__ xb,
                       const __hip_bfloat16* __restrict__ wt,
                       const float* __restrict__ pe2,
                       const float* __restrict__ tc,
                       const float* __restrict__ tcw,
                       float* __restrict__ out) {
    __shared__ alignas(16) __hip_bfloat16 As[128 * 64];
    __shared__ alignas(16) __hip_bfloat16 Bs[128 * 64];

    const int bid = blockIdx.x;          // 1024 blocks
    const int mt = bid >> 2, nt = bid & 3;
    const int bb = mt >> 4;              // batch
    const int s0 = (mt & 15) << 7;       // s-tile origin
    const int d0 = nt << 7;              // d-tile origin
    const int tid = threadIdx.x;
    const int lane = tid & 63;
    const int w = tid >> 6;
    const int wr = w >> 1, wc = w & 1;   // 2x2 waves of 64x64 output each

    f32x4 acc[4][4] = {};

    for (int k = 0; k < 3; ++k) {
        // stage A: 128 rows x 64 bf16 (128B rows) = 1024 x 16B chunks
#pragma unroll
        for (int i = 0; i < 4; ++i) {
            int q = tid + i * 256;
            int row = q >> 3;
            int c16 = (q & 7) ^ (row & 7);                     // src pre-swizzle
            int ssrc = (s0 + row + k + 2047) & 2047;           // (s+k-1) mod S
            const __hip_bfloat16* src =
                xb + (size_t)(bb * 2048 + ssrc) * 64 + c16 * 8;
            __builtin_amdgcn_global_load_lds((GV*)src, (LV*)(As + q * 8), 16, 0, 0);
        }
        // stage B: 128 d-rows x 64 bf16 of wt
#pragma unroll
        for (int i = 0; i < 4; ++i) {
            int q = tid + i * 256;
            int row = q >> 3;
            int c16 = (q & 7) ^ (row & 7);
            const __hip_bfloat16* src =
                wt + (size_t)(d0 + row) * 192 + k * 64 + c16 * 8;
            __builtin_amdgcn_global_load_lds((GV*)src, (LV*)(Bs + q * 8), 16, 0, 0);
        }
        __syncthreads();   // compiler emits vmcnt(0) drain here

#pragma unroll
        for (int kk = 0; kk < 2; ++kk) {           // two K=32 slices of BK=64
            const int colb = kk * 64 + ((lane >> 4) << 4);     // byte col in row
            bfrag af[4], bfv[4];
#pragma unroll
            for (int m4 = 0; m4 < 4; ++m4) {
                int row = wr * 64 + m4 * 16 + (lane & 15);
                af[m4] = *(const bfrag*)((const char*)As + row * 128 +
                                         (colb ^ ((row & 7) << 4)));
            }
#pragma unroll
            for (int n4 = 0; n4 < 4; ++n4) {
                int row = wc * 64 + n4 * 16 + (lane & 15);
                bfv[n4] = *(const bfrag*)((const char*)Bs + row * 128 +
                                          (colb ^ ((row & 7) << 4)));
            }
#pragma unroll
            for (int m4 = 0; m4 < 4; ++m4)
#pragma unroll
                for (int n4 = 0; n4 < 4; ++n4)
                    acc[m4][n4] = __builtin_amdgcn_mfma_f32_16x16x32_bf16(
                        af[m4], bfv[n4], acc[m4][n4], 0, 0, 0);
        }
        __syncthreads();
    }

    // epilogue: out = acc + pe2[s][d] + tc[b][s]*tcw[d]
#pragma unroll
    for (int n4 = 0; n4 < 4; ++n4) {
        const int col = d0 + wc * 64 + n4 * 16 + (lane & 15);
        const float tw = tcw[col];
#pragma unroll
        for (int m4 = 0; m4 < 4; ++m4) {
#pragma unroll
            for (int r = 0; r < 4; ++r) {
                int s = s0 + wr * 64 + m4 * 16 + ((lane >> 4) << 2) + r;
                size_t o = (size_t)(bb * 2048 + s) * 512 + col;
                out[o] = acc[m4][n4][r] + pe2[(size_t)s * 512 + col] +
                         tc[bb * 2048 + s] * tw;
            }
        }
    }
}

extern "C" void kernel_launch(void* const* d_in, const int* in_sizes, int n_in,
                              void* d_out, int out_size, void* d_ws, size_t ws_size,
                              hipStream_t stream) {
    const float* x   = (const float*)d_in[0];   // (16,2048,64)
    const float* cw  = (const float*)d_in[1];   // (512,64,3)
    const float* tcw = (const float*)d_in[2];   // (512,1)
    const float* tcb = (const float*)d_in[3];   // (512,)
    float* out = (float*)d_out;

    char* ws = (char*)d_ws;
    __hip_bfloat16* xb  = (__hip_bfloat16*)(ws);             // 4,194,304 B
    __hip_bfloat16* wt  = (__hip_bfloat16*)(ws + 4194304);   //   196,608 B
    float* pe2          = (float*)(ws + 4390912);            // 4,194,304 B
    float* norms        = (float*)(ws + 8585216);            //   131,072 B
    float* tc           = (float*)(ws + 8716288);            //   131,072 B

    hipLaunchKernelGGL(k_norms_xb, dim3(8192), dim3(256), 0, stream, x, norms, xb);
    hipLaunchKernelGGL(k_wt,       dim3(384),  dim3(256), 0, stream, cw, wt);
    hipLaunchKernelGGL(k_pe,       dim3(2048), dim3(256), 0, stream, tcb, pe2);
    hipLaunchKernelGGL(k_tc,       dim3(8192), dim3(256), 0, stream, norms, tc);
    hipLaunchKernelGGL(k_gemm,     dim3(1024), dim3(256), 0, stream,
                       xb, wt, pe2, tc, tcw, out);
}

// Round 2
// 60.774 us; speedup vs baseline: 1.4228x; 1.4228x over previous
//
#include <hip/hip_runtime.h>
#include <hip/hip_bf16.h>

typedef __attribute__((ext_vector_type(8))) short bfrag;   // 8 bf16
typedef __attribute__((ext_vector_type(4))) float f32x4;

typedef __attribute__((address_space(1))) const void GV;
typedef __attribute__((address_space(3))) void LV;

#define SLEN 2048
#define DM 512

// ================= fused prep: norms+xb | wt | pe2 =================
// blocks [0,8192): norms + x->bf16     (2M elements)
// blocks [8192,8576): conv_w -> wt[d][k*64+c]
// blocks [8576,10624): pe2[s][d] = PE(s,d) + tc_b[d]
__global__ void k_prep(const float* __restrict__ x,
                       const float* __restrict__ w,
                       const float* __restrict__ tcb,
                       float* __restrict__ norms,
                       __hip_bfloat16* __restrict__ xb,
                       __hip_bfloat16* __restrict__ wt,
                       float* __restrict__ pe2) {
    int blk = blockIdx.x;
    if (blk < 8192) {
        int tid = blk * 256 + threadIdx.x;
        float v = x[tid];
        xb[tid] = __float2bfloat16(v);
        float a = fabsf(v);
#pragma unroll
        for (int off = 32; off; off >>= 1) a += __shfl_xor(a, off);
        if ((threadIdx.x & 63) == 0) norms[tid >> 6] = a;
    } else if (blk < 8576) {
        int i = (blk - 8192) * 256 + threadIdx.x;       // 98304
        int d = i / 192, kk = i % 192;
        int c = kk & 63, k = kk >> 6;
        wt[i] = __float2bfloat16(w[d * 192 + c * 3 + k]);
    } else {
        int i = (blk - 8576) * 256 + threadIdx.x;       // 524288
        int s = i >> 8, h = i & 255;
        float dv = expf((float)(2 * h) * (-9.210340371976184f / 512.0f));
        float sv, cv;
        sincosf((float)s * dv, &sv, &cv);
        pe2[s * 512 + 2 * h]     = sv + tcb[2 * h];
        pe2[s * 512 + 2 * h + 1] = cv + tcb[2 * h + 1];
    }
}

// ---------- tc[b][t]: wave-per-t backward ballot scan (exact) ----------
__global__ void k_tc(const float* __restrict__ norms, float* __restrict__ tc) {
    int gid = blockIdx.x * 256 + threadIdx.x;
    int wave = gid >> 6;
    int lane = threadIdx.x & 63;
    int b = wave >> 11, t = wave & 2047;
    const float* nb = norms + b * 2048;
    float thresh = 0.7f * (nb[t] + 1e-8f);
    int res = 0;
    for (int base = t - 1; base >= 0; base -= 64) {
        int s = base - lane;
        bool pred = (s >= 0) && (nb[s] < thresh);
        unsigned long long m = __ballot(pred);
        if (m) {
            int l0 = __ffsll(m) - 1;       // smallest lane = largest s
            res = t - (base - l0);
            break;
        }
    }
    if (lane == 0) tc[wave] = (float)res;
}

// =========== conv-GEMM, M=d (64-tile), N=s (128-tile), K=192 ===========
// A = wt (rows d, 384B pitch), B = xb rows s0-1..s0+128 staged ONCE
// (taps share the window; tap k reads local row sl+k). One barrier.
// Output frag: col(lane&15)=s, rows(reg)=4 consecutive d -> float4 I/O.
__launch_bounds__(256)
__global__ void k_gemm(const __hip_bfloat16* __restrict__ xb,
                       const __hip_bfloat16* __restrict__ wt,
                       const float* __restrict__ pe2,
                       const float* __restrict__ tc,
                       const float* __restrict__ tcw,
                       float* __restrict__ out) {
    __shared__ alignas(16) __hip_bfloat16 As[64 * 192];    // 24.0 KB
    __shared__ alignas(16) __hip_bfloat16 Bs[130 * 64];    // 16.25 KB

    int bid = blockIdx.x;
    int swz = (bid & 7) * 256 + (bid >> 3);      // XCD swizzle, 2048%8==0
    const int d0 = (swz & 7) * 64;
    const int st = swz >> 3;                     // 0..255
    const int bb = st >> 4;
    const int s0 = (st & 15) * 128;
    const int tid = threadIdx.x;
    const int lane = tid & 63;
    const int wv = tid >> 6;
    const int wd = wv >> 1, ws = wv & 1;         // wave tile: 32(d) x 64(s)

    // ---- stage A (wt): 64 rows x 24 16B-chunks, src pre-swizzled ----
#pragma unroll
    for (int i = 0; i < 6; ++i) {
        int q = tid + i * 256;                   // < 1536
        int row = q / 24, u = q - row * 24;
        int us = u ^ (row & 7);
        const __hip_bfloat16* src = wt + (size_t)(d0 + row) * 192 + us * 8;
        __builtin_amdgcn_global_load_lds((GV*)src, (LV*)(As + q * 8), 16, 0, 0);
    }
    // ---- stage B (xb): 130 rows x 8 chunks, circular window s0-1.. ----
#pragma unroll
    for (int i = 0; i < 5; ++i) {
        int q = tid + i * 256;
        if (q < 1040) {
            int row = q >> 3, u = q & 7;
            int us = u ^ (row & 7);
            int sg = (s0 - 1 + row) & 2047;
            const __hip_bfloat16* src =
                xb + (size_t)((bb << 11) + sg) * 64 + us * 8;
            __builtin_amdgcn_global_load_lds((GV*)src, (LV*)(Bs + q * 8), 16, 0, 0);
        }
    }
    __syncthreads();

    f32x4 acc[2][4] = {};
    const int lhi = lane >> 4, ll = lane & 15;
#pragma unroll
    for (int k = 0; k < 3; ++k) {
#pragma unroll
        for (int kc = 0; kc < 2; ++kc) {
            bfrag af[2], bf[4];
            const int colA = k * 128 + kc * 64 + lhi * 16;   // byte in 384B row
#pragma unroll
            for (int m = 0; m < 2; ++m) {
                int rd = wd * 32 + m * 16 + ll;
                af[m] = *(const bfrag*)((const char*)As + rd * 384 +
                                        (colA ^ ((rd & 7) << 4)));
            }
            const int colB = kc * 64 + lhi * 16;             // byte in 128B row
#pragma unroll
            for (int n = 0; n < 4; ++n) {
                int rl = ws * 64 + n * 16 + ll + k;          // 0..129
                bf[n] = *(const bfrag*)((const char*)Bs + rl * 128 +
                                        (colB ^ ((rl & 7) << 4)));
            }
#pragma unroll
            for (int m = 0; m < 2; ++m)
#pragma unroll
                for (int n = 0; n < 4; ++n)
                    acc[m][n] = __builtin_amdgcn_mfma_f32_16x16x32_bf16(
                        af[m], bf[n], acc[m][n], 0, 0, 0);
        }
    }

    // ---- epilogue: float4 everywhere ----
    f32x4 tw[2];
#pragma unroll
    for (int m = 0; m < 2; ++m)
        tw[m] = *(const f32x4*)&tcw[d0 + wd * 32 + m * 16 + lhi * 4];
#pragma unroll
    for (int n = 0; n < 4; ++n) {
        const int sCol = s0 + ws * 64 + n * 16 + ll;
        const float tcv = tc[(bb << 11) + sCol];
        const size_t orow = ((size_t)(bb << 11) + sCol) * 512;
#pragma unroll
        for (int m = 0; m < 2; ++m) {
            const int dbase = d0 + wd * 32 + m * 16 + lhi * 4;
            f32x4 pw = *(const f32x4*)&pe2[sCol * 512 + dbase];
            f32x4 r = acc[m][n] + pw + tcv * tw[m];
            *(f32x4*)&out[orow + dbase] = r;
        }
    }
}

extern "C" void kernel_launch(void* const* d_in, const int* in_sizes, int n_in,
                              void* d_out, int out_size, void* d_ws, size_t ws_size,
                              hipStream_t stream) {
    const float* x   = (const float*)d_in[0];   // (16,2048,64)
    const float* cw  = (const float*)d_in[1];   // (512,64,3)
    const float* tcw = (const float*)d_in[2];   // (512,1)
    const float* tcb = (const float*)d_in[3];   // (512,)
    float* out = (float*)d_out;

    char* ws = (char*)d_ws;
    __hip_bfloat16* xb  = (__hip_bfloat16*)(ws);             // 4,194,304 B
    __hip_bfloat16* wt  = (__hip_bfloat16*)(ws + 4194304);   //   196,608 B
    float* pe2          = (float*)(ws + 4390912);            // 4,194,304 B
    float* norms        = (float*)(ws + 8585216);            //   131,072 B
    float* tc           = (float*)(ws + 8716288);            //   131,072 B

    hipLaunchKernelGGL(k_prep, dim3(10624), dim3(256), 0, stream,
                       x, cw, tcb, norms, xb, wt, pe2);
    hipLaunchKernelGGL(k_tc,   dim3(8192),  dim3(256), 0, stream, norms, tc);
    hipLaunchKernelGGL(k_gemm, dim3(2048),  dim3(256), 0, stream,
                       xb, wt, pe2, tc, tcw, out);
}

// Round 4
// 48.805 us; speedup vs baseline: 1.7718x; 1.2452x over previous
//
#include <hip/hip_runtime.h>
#include <hip/hip_bf16.h>

typedef __attribute__((ext_vector_type(8))) short bfrag;   // 8 bf16
typedef __attribute__((ext_vector_type(4))) float f32x4;

typedef __attribute__((address_space(1))) const void GV;
typedef __attribute__((address_space(3))) void LV;

// ================= fused prep: norms+xb | wt | pe2 (all float4) =========
// blocks [0,2048): x float4 -> xb bf16x4 + L1 norms (16 lanes/row)
// blocks [2048,2432): conv_w -> wt[d][k*64+c]
// blocks [2432,3456): pe2[s][d] = PE(s,d)+tc_b[d], float4 per thread
__global__ void k_prep(const float* __restrict__ x,
                       const float* __restrict__ w,
                       const float* __restrict__ tcb,
                       float* __restrict__ norms,
                       __hip_bfloat16* __restrict__ xb,
                       __hip_bfloat16* __restrict__ wt,
                       float* __restrict__ pe2) {
    int blk = blockIdx.x;
    if (blk < 2048) {
        int i = blk * 256 + threadIdx.x;            // 524288 quads
        f32x4 v = *(const f32x4*)&x[i * 4];
        __hip_bfloat16 h[4];
        h[0] = __float2bfloat16(v.x);
        h[1] = __float2bfloat16(v.y);
        h[2] = __float2bfloat16(v.z);
        h[3] = __float2bfloat16(v.w);
        *(short4*)&xb[i * 4] = *(const short4*)h;
        float a = fabsf(v.x) + fabsf(v.y) + fabsf(v.z) + fabsf(v.w);
        a += __shfl_xor(a, 1);
        a += __shfl_xor(a, 2);
        a += __shfl_xor(a, 4);
        a += __shfl_xor(a, 8);                      // 16-lane row reduce
        if ((threadIdx.x & 15) == 0) norms[i >> 4] = a;
    } else if (blk < 2432) {
        int i = (blk - 2048) * 256 + threadIdx.x;   // 98304
        int d = i / 192, kk = i - d * 192;
        int c = kk & 63, k = kk >> 6;
        wt[i] = __float2bfloat16(w[d * 192 + c * 3 + k]);
    } else {
        int j = (blk - 2432) * 256 + threadIdx.x;   // 262144 d-quads
        int s = j >> 7, q = j & 127;                // d = 4q
        f32x4 tb = *(const f32x4*)&tcb[q * 4];
        float dv0 = expf((float)(4 * q)     * (-9.210340371976184f / 512.0f));
        float dv1 = expf((float)(4 * q + 2) * (-9.210340371976184f / 512.0f));
        float s0v, c0v, s1v, c1v;
        sincosf((float)s * dv0, &s0v, &c0v);
        sincosf((float)s * dv1, &s1v, &c1v);
        f32x4 r = {s0v + tb.x, c0v + tb.y, s1v + tb.z, c1v + tb.w};
        *(f32x4*)&pe2[s * 512 + q * 4] = r;
    }
}

// ---------- tc[b][t]: wave-per-t, 256-wide aligned float4 windows ----------
__global__ void k_tc(const float* __restrict__ norms, float* __restrict__ tc) {
    int gid = blockIdx.x * 256 + threadIdx.x;
    int wave = gid >> 6;                  // 32768 = (b,t)
    int lane = threadIdx.x & 63;
    int b = wave >> 11, t = wave & 2047;
    const float* nb = norms + (b << 11);
    float thresh = 0.7f * (nb[t] + 1e-8f);
    int res = 0;
    for (int W = (t - 1) >> 8; W >= 0; --W) {       // t=0 -> W=-1, skipped
        int sBase = W * 256 + 4 * lane;
        f32x4 v = *(const f32x4*)&nb[sBase];        // 16B aligned
        int best = -1;
        if (sBase + 0 < t && v.x < thresh) best = sBase + 0;
        if (sBase + 1 < t && v.y < thresh) best = sBase + 1;
        if (sBase + 2 < t && v.z < thresh) best = sBase + 2;
        if (sBase + 3 < t && v.w < thresh) best = sBase + 3;
        unsigned long long m = __ballot(best >= 0);
        if (m) {                                    // highest lane = largest s
            int L = 63 - __clzll(m);
            int smax = __shfl(best, L);
            res = t - smax;
            break;
        }
    }
    if (lane == 0) tc[wave] = (float)res;
}

// =========== conv-GEMM: A (wt) direct from L2, B (xb) in LDS ===========
// 64(d) x 128(s) tile, K=192 (3 taps x 64ch). Bs = circular 130-row window.
// XCD x owns s-tiles {2x,2x+1} for all (b,d) -> pe2/xb slices L2-resident.
__launch_bounds__(256, 4)
__global__ void k_gemm(const __hip_bfloat16* __restrict__ xb,
                       const __hip_bfloat16* __restrict__ wt,
                       const float* __restrict__ pe2,
                       const float* __restrict__ tc,
                       const float* __restrict__ tcw,
                       float* __restrict__ out) {
    __shared__ alignas(16) __hip_bfloat16 Bs[130 * 64];    // 16.25 KB

    const int bid = blockIdx.x;
    const int xcd = bid & 7, u = bid >> 3;       // dispatch round-robins XCDs
    const int st = (xcd << 1) | (u & 1);
    const int bb = (u >> 1) & 15;
    const int dt = u >> 5;
    const int d0 = dt << 6;
    const int s0 = st << 7;
    const int tid = threadIdx.x;
    const int lane = tid & 63;
    const int wv = tid >> 6;
    const int wd = wv >> 1, ws = wv & 1;         // wave tile: 32(d) x 64(s)
    const int lhi = lane >> 4, ll = lane & 15;

    // ---- stage B (xb): 130 rows x 8 16B-chunks, circular window ----
#pragma unroll
    for (int i = 0; i < 5; ++i) {
        int q = tid + i * 256;
        if (q < 1040) {
            int row = q >> 3, uu = q & 7;
            int us = uu ^ (row & 7);                       // src pre-swizzle
            int sg = (s0 - 1 + row) & 2047;
            const __hip_bfloat16* src =
                xb + (size_t)((bb << 11) + sg) * 64 + us * 8;
            __builtin_amdgcn_global_load_lds((GV*)src, (LV*)(Bs + q * 8), 16, 0, 0);
        }
    }

    // ---- A fragments for tap 0 straight from global (wt is L2-hot) ----
    const __hip_bfloat16* wbase =
        wt + (size_t)(d0 + wd * 32 + ll) * 192 + lhi * 8;
    bfrag af[2][2];                               // [kc][m]
#pragma unroll
    for (int kc = 0; kc < 2; ++kc)
#pragma unroll
        for (int m = 0; m < 2; ++m)
            af[kc][m] = *(const bfrag*)(wbase + m * 16 * 192 + kc * 32);

    __syncthreads();

    f32x4 acc[2][4] = {};
#pragma unroll
    for (int k = 0; k < 3; ++k) {
        bfrag an[2][2];
        if (k < 2) {                              // prefetch tap k+1
#pragma unroll
            for (int kc = 0; kc < 2; ++kc)
#pragma unroll
                for (int m = 0; m < 2; ++m)
                    an[kc][m] = *(const bfrag*)(wbase + m * 16 * 192 +
                                                (k + 1) * 64 + kc * 32);
        }
#pragma unroll
        for (int kc = 0; kc < 2; ++kc) {
            bfrag bf[4];
            const int colB = kc * 64 + lhi * 16;          // byte in 128B row
#pragma unroll
            for (int n = 0; n < 4; ++n) {
                int rl = ws * 64 + n * 16 + ll + k;       // 0..129
                bf[n] = *(const bfrag*)((const char*)Bs + rl * 128 +
                                        (colB ^ ((rl & 7) << 4)));
            }
#pragma unroll
            for (int m = 0; m < 2; ++m)
#pragma unroll
                for (int n = 0; n < 4; ++n)
                    acc[m][n] = __builtin_amdgcn_mfma_f32_16x16x32_bf16(
                        af[kc][m], bf[n], acc[m][n], 0, 0, 0);
        }
#pragma unroll
        for (int kc = 0; kc < 2; ++kc)
#pragma unroll
            for (int m = 0; m < 2; ++m)
                af[kc][m] = an[kc][m];
    }

    // ---- epilogue: float4 everywhere ----
    f32x4 tw[2];
#pragma unroll
    for (int m = 0; m < 2; ++m)
        tw[m] = *(const f32x4*)&tcw[d0 + wd * 32 + m * 16 + lhi * 4];
#pragma unroll
    for (int n = 0; n < 4; ++n) {
        const int sCol = s0 + ws * 64 + n * 16 + ll;
        const float tcv = tc[(bb << 11) + sCol];
        const size_t orow = ((size_t)(bb << 11) + sCol) * 512;
#pragma unroll
        for (int m = 0; m < 2; ++m) {
            const int dbase = d0 + wd * 32 + m * 16 + lhi * 4;
            f32x4 pw = *(const f32x4*)&pe2[sCol * 512 + dbase];
            f32x4 r = acc[m][n] + pw + tcv * tw[m];
            *(f32x4*)&out[orow + dbase] = r;
        }
    }
}

extern "C" void kernel_launch(void* const* d_in, const int* in_sizes, int n_in,
                              void* d_out, int out_size, void* d_ws, size_t ws_size,
                              hipStream_t stream) {
    const float* x   = (const float*)d_in[0];   // (16,2048,64)
    const float* cw  = (const float*)d_in[1];   // (512,64,3)
    const float* tcw = (const float*)d_in[2];   // (512,1)
    const float* tcb = (const float*)d_in[3];   // (512,)
    float* out = (float*)d_out;

    char* ws = (char*)d_ws;
    __hip_bfloat16* xb  = (__hip_bfloat16*)(ws);             // 4,194,304 B
    __hip_bfloat16* wt  = (__hip_bfloat16*)(ws + 4194304);   //   196,608 B
    float* pe2          = (float*)(ws + 4390912);            // 4,194,304 B
    float* norms        = (float*)(ws + 8585216);            //   131,072 B
    float* tc           = (float*)(ws + 8716288);            //   131,072 B

    hipLaunchKernelGGL(k_prep, dim3(3456), dim3(256), 0, stream,
                       x, cw, tcb, norms, xb, wt, pe2);
    hipLaunchKernelGGL(k_tc,   dim3(8192), dim3(256), 0, stream, norms, tc);
    hipLaunchKernelGGL(k_gemm, dim3(2048), dim3(256), 0, stream,
                       xb, wt, pe2, tc, tcw, out);
}